// Round 12
// baseline (79.966 us; speedup 1.0000x reference)
//
#include <hip/hip_runtime.h>
#include <hip/hip_bf16.h>

// Problem sizes (fixed by the reference)
#define S_LEN 256     // sequence length (t)
#define DM    512     // d_model (k / d)
#define DR    512     // d_rnn (s)

typedef float f4 __attribute__((ext_vector_type(4)));
typedef float f2 __attribute__((ext_vector_type(2)));

// ws layout (floats):
//   xT  : [512][256]     at 0       (131072)
//   acT : f2[512][256]   at 131072  (262144)

__global__ __launch_bounds__(256) void k_transpose_x(const float* __restrict__ x,
                                                     float* __restrict__ xT) {
    __shared__ float tile[32][33];
    const int k0 = blockIdx.x * 32;
    const int t0 = blockIdx.y * 32;
    const int lx = threadIdx.x & 31;
    const int ly = threadIdx.x >> 5;
#pragma unroll
    for (int i = 0; i < 32; i += 8)
        tile[ly + i][lx] = x[(t0 + ly + i) * DM + k0 + lx];
    __syncthreads();
#pragma unroll
    for (int i = 0; i < 32; i += 8)
        xT[(k0 + ly + i) * S_LEN + t0 + lx] = tile[lx][ly + i];
}

// grid(256): block g computes GEMM rows {2g, 2g+1, 512+2g, 512+2g+1} over all t,
// then applies the sigmoid/softplus/exp epilogue and writes acT[s][t] = {a, c}.
__global__ __launch_bounds__(256) void k_gemm_act(const float* __restrict__ xT,
                                                  const float* __restrict__ W1,
                                                  const float* __restrict__ b1,
                                                  const float* __restrict__ Lam,
                                                  f2* __restrict__ acT) {
    const int g  = blockIdx.x;       // 0..255
    const int t  = threadIdx.x;      // lane axis = t (coalesced xT loads)
    const int r0 = 2 * g;

    float acc0 = 0.f, acc1 = 0.f, acc2 = 0.f, acc3 = 0.f;
    const float* __restrict__ xb = xT + t;
    const float* __restrict__ w0 = W1 + (r0)       * DM;   // wave-uniform → s_loads
    const float* __restrict__ w1 = W1 + (r0 + 1)   * DM;
    const float* __restrict__ w2 = W1 + (512 + r0) * DM;
    const float* __restrict__ w3 = W1 + (513 + r0) * DM;

#pragma unroll 8
    for (int k = 0; k < DM; ++k) {
        const float xv = xb[k * S_LEN];
        acc0 = fmaf(xv, w0[k], acc0);
        acc1 = fmaf(xv, w1[k], acc1);
        acc2 = fmaf(xv, w2[k], acc2);
        acc3 = fmaf(xv, w3[k], acc3);
    }

#pragma unroll
    for (int j = 0; j < 2; ++j) {
        const float pre_i = (j ? acc1 : acc0) + b1[r0 + j];
        const float pre_r = (j ? acc3 : acc2) + b1[512 + r0 + j];
        const float inp = 1.f / (1.f + expf(-pre_i));
        const float rec = 1.f / (1.f + expf(-pre_r));
        const float sp  = log1pf(expf(Lam[r0 + j]));
        const float a   = expf(-8.f * sp * rec);
        const float c   = sqrtf(fmaxf(1.f - a * a, 0.f)) * inp;
        f2 ac; ac.x = a; ac.y = c;
        acT[(r0 + j) * S_LEN + t] = ac;
    }
}

// grid(256) x 256: R11 loop verbatim, but stores are PLAIN (cached) instead of
// nontemporal: y goes through L2 and the L2 write-back engine batches dirty
// lines to DRAM in row-friendly order (chip-level write combining), which is
// how the 7 TB/s fill kernel drains. nt bypassed that and pinned us at ~4.1.
__global__ __launch_bounds__(256) void k_rec(const float* __restrict__ x,
                                             const float* __restrict__ state0,
                                             const f2* __restrict__ acT,
                                             f4* __restrict__ out4) {
    const int bx   = blockIdx.x;
    const int sp   = (bx & 7) * 32 + (bx >> 3);   // bijective XCD s-banding (harmless)
    const int tid  = threadIdx.x;
    const int half = tid >> 7;           // 0 or 1
    const int s    = sp * 2 + half;
    const int dq   = tid & 127;          // d/4

    __shared__ f2 ac_l[2][S_LEN];        // {a, c} per (half, t)
    f2* lf = &ac_l[0][0];
    lf[tid]       = acT[sp * 2 * S_LEN + tid];
    lf[tid + 256] = acT[sp * 2 * S_LEN + tid + 256];
    __syncthreads();

    const f4* __restrict__ st4 = reinterpret_cast<const f4*>(state0);
    f4 h = st4[s * 128 + dq];

    const f4* __restrict__ x4 = reinterpret_cast<const f4*>(x);
    f4 xv = x4[dq];                      // t = 0 prefetch

#pragma unroll 4
    for (int t = 0; t < S_LEN; ++t) {
        f4 xn;
        if (t + 1 < S_LEN) xn = x4[(t + 1) * 128 + dq];
        else xn = (f4)0.f;

        const f2 ac = ac_l[half][t];               // LDS broadcast (wave-uniform)
        const float at = ac.x, ct = ac.y;
        h.x = fmaf(at, h.x, ct * xv.x);
        h.y = fmaf(at, h.y, ct * xv.y);
        h.z = fmaf(at, h.z, ct * xv.z);
        h.w = fmaf(at, h.w, ct * xv.w);

        out4[(t * DR + s) * 128 + dq] = h;         // PLAIN store (via L2)
        xv = xn;
    }
    // final state
    out4[(S_LEN * DR) * 128 + s * 128 + dq] = h;
}

extern "C" void kernel_launch(void* const* d_in, const int* in_sizes, int n_in,
                              void* d_out, int out_size, void* d_ws, size_t ws_size,
                              hipStream_t stream) {
    const float* x      = (const float*)d_in[0];
    const float* state0 = (const float*)d_in[1];
    const float* W1     = (const float*)d_in[2];
    const float* b1     = (const float*)d_in[3];
    const float* Lam    = (const float*)d_in[4];

    float* ws  = (float*)d_ws;
    float* xT  = ws;                      // 131072 floats
    f2*    acT = (f2*)(ws + 131072);      // 131072 f2

    f4* out4 = (f4*)d_out;

    k_transpose_x<<<dim3(16, 8), 256, 0, stream>>>(x, xT);
    k_gemm_act<<<dim3(256), 256, 0, stream>>>(xT, W1, b1, Lam, acT);
    k_rec<<<dim3(256), 256, 0, stream>>>(x, state0, acT, out4);
}

// Round 13
// 76.336 us; speedup vs baseline: 1.0475x; 1.0475x over previous
//
#include <hip/hip_runtime.h>
#include <hip/hip_bf16.h>

// Problem sizes (fixed by the reference)
#define S_LEN 256     // sequence length (t)
#define DM    512     // d_model (k / d)
#define DR    512     // d_rnn (s)

typedef float f4 __attribute__((ext_vector_type(4)));
typedef float f2 __attribute__((ext_vector_type(2)));

// ws layout (floats):
//   xT  : [512][256]     at 0       (131072)
//   acT : f2[512][256]   at 131072  (262144)

__global__ __launch_bounds__(256) void k_transpose_x(const float* __restrict__ x,
                                                     float* __restrict__ xT) {
    __shared__ float tile[32][33];
    const int k0 = blockIdx.x * 32;
    const int t0 = blockIdx.y * 32;
    const int lx = threadIdx.x & 31;
    const int ly = threadIdx.x >> 5;
#pragma unroll
    for (int i = 0; i < 32; i += 8)
        tile[ly + i][lx] = x[(t0 + ly + i) * DM + k0 + lx];
    __syncthreads();
#pragma unroll
    for (int i = 0; i < 32; i += 8)
        xT[(k0 + ly + i) * S_LEN + t0 + lx] = tile[lx][ly + i];
}

// grid(256): block g computes GEMM rows {2g, 2g+1, 512+2g, 512+2g+1} over all t,
// then applies the sigmoid/softplus/exp epilogue and writes acT[s][t] = {a, c}.
__global__ __launch_bounds__(256) void k_gemm_act(const float* __restrict__ xT,
                                                  const float* __restrict__ W1,
                                                  const float* __restrict__ b1,
                                                  const float* __restrict__ Lam,
                                                  f2* __restrict__ acT) {
    const int g  = blockIdx.x;       // 0..255
    const int t  = threadIdx.x;      // lane axis = t (coalesced xT loads)
    const int r0 = 2 * g;

    float acc0 = 0.f, acc1 = 0.f, acc2 = 0.f, acc3 = 0.f;
    const float* __restrict__ xb = xT + t;
    const float* __restrict__ w0 = W1 + (r0)       * DM;   // wave-uniform → s_loads
    const float* __restrict__ w1 = W1 + (r0 + 1)   * DM;
    const float* __restrict__ w2 = W1 + (512 + r0) * DM;
    const float* __restrict__ w3 = W1 + (513 + r0) * DM;

#pragma unroll 8
    for (int k = 0; k < DM; ++k) {
        const float xv = xb[k * S_LEN];
        acc0 = fmaf(xv, w0[k], acc0);
        acc1 = fmaf(xv, w1[k], acc1);
        acc2 = fmaf(xv, w2[k], acc2);
        acc3 = fmaf(xv, w3[k], acc3);
    }

#pragma unroll
    for (int j = 0; j < 2; ++j) {
        const float pre_i = (j ? acc1 : acc0) + b1[r0 + j];
        const float pre_r = (j ? acc3 : acc2) + b1[512 + r0 + j];
        const float inp = 1.f / (1.f + expf(-pre_i));
        const float rec = 1.f / (1.f + expf(-pre_r));
        const float sp  = log1pf(expf(Lam[r0 + j]));
        const float a   = expf(-8.f * sp * rec);
        const float c   = sqrtf(fmaxf(1.f - a * a, 0.f)) * inp;
        f2 ac; ac.x = a; ac.y = c;
        acT[(r0 + j) * S_LEN + t] = ac;
    }
}

// grid(256) x 256: R11 structure, but the 1-deep x prefetch becomes a 4-step
// double-buffered register window (xa/xb). vmcnt is in-order, so the consume
// wait for a window's 4 loads (issued one half-iteration earlier, with 4
// loads + 4 stores younger) is vmcnt(~8): per-window ONE exposed load
// latency amortized over 4 steps instead of per-step, while staying under
// the per-wave VMEM queue (~12 outstanding; R9's 48 overflowed it).
// h rotates through 8 registers so stores never force WAR waits.
__global__ __launch_bounds__(256) void k_rec(const float* __restrict__ x,
                                             const float* __restrict__ state0,
                                             const f2* __restrict__ acT,
                                             f4* __restrict__ out4) {
    const int bx   = blockIdx.x;
    const int sp   = (bx & 7) * 32 + (bx >> 3);   // bijective XCD s-banding
    const int tid  = threadIdx.x;
    const int half = tid >> 7;           // 0 or 1
    const int s    = sp * 2 + half;
    const int dq   = tid & 127;          // d/4

    __shared__ f2 ac_l[2][S_LEN];        // {a, c} per (half, t)
    f2* lf = &ac_l[0][0];
    lf[tid]       = acT[sp * 2 * S_LEN + tid];
    lf[tid + 256] = acT[sp * 2 * S_LEN + tid + 256];

    const f4* __restrict__ st4 = reinterpret_cast<const f4*>(state0);
    const f4* __restrict__ x4  = reinterpret_cast<const f4*>(x);

    f4 h0, h1, h2, h3, h4, h5, h6;
    f4 h7 = st4[s * 128 + dq];           // rotating state; h7 = entry value

    f4 xa0, xa1, xa2, xa3, xb0, xb1, xb2, xb3;

#define LOADA(W) {                                                           \
        xa0 = x4[((W) * 4 + 0) * 128 + dq];                                  \
        xa1 = x4[((W) * 4 + 1) * 128 + dq];                                  \
        xa2 = x4[((W) * 4 + 2) * 128 + dq];                                  \
        xa3 = x4[((W) * 4 + 3) * 128 + dq];                                  \
    }
#define LOADB(W) {                                                           \
        xb0 = x4[((W) * 4 + 0) * 128 + dq];                                  \
        xb1 = x4[((W) * 4 + 1) * 128 + dq];                                  \
        xb2 = x4[((W) * 4 + 2) * 128 + dq];                                  \
        xb3 = x4[((W) * 4 + 3) * 128 + dq];                                  \
    }
#define ST1(HP, HN, T, XV) {                                                 \
        const f2 ac = ac_l[half][T];           /* wave-uniform LDS */        \
        HN.x = fmaf(ac.x, HP.x, ac.y * XV.x);                                \
        HN.y = fmaf(ac.x, HP.y, ac.y * XV.y);                                \
        HN.z = fmaf(ac.x, HP.z, ac.y * XV.z);                                \
        HN.w = fmaf(ac.x, HP.w, ac.y * XV.w);                                \
        __builtin_nontemporal_store(HN, &out4[((T) * DR + s) * 128 + dq]);   \
    }
#define COMPA(W)                                                             \
        ST1(h7, h0, (W) * 4 + 0, xa0) ST1(h0, h1, (W) * 4 + 1, xa1)          \
        ST1(h1, h2, (W) * 4 + 2, xa2) ST1(h2, h3, (W) * 4 + 3, xa3)
#define COMPB(W)                                                             \
        ST1(h3, h4, (W) * 4 + 0, xb0) ST1(h4, h5, (W) * 4 + 1, xb1)          \
        ST1(h5, h6, (W) * 4 + 2, xb2) ST1(h6, h7, (W) * 4 + 3, xb3)

    LOADA(0)
    __syncthreads();                     // ac_l ready (drains prologue loads only)

    for (int p = 0; p < 31; ++p) {       // windows 0..61, branch-free body
        LOADB(2 * p + 1)
        COMPA(2 * p)
        LOADA(2 * p + 2)
        COMPB(2 * p + 1)
    }
    LOADB(63)
    COMPA(62)
    COMPB(63)

#undef LOADA
#undef LOADB
#undef ST1
#undef COMPA
#undef COMPB

    // final state (in h7 after 64 windows)
    out4[(S_LEN * DR) * 128 + s * 128 + dq] = h7;
}

extern "C" void kernel_launch(void* const* d_in, const int* in_sizes, int n_in,
                              void* d_out, int out_size, void* d_ws, size_t ws_size,
                              hipStream_t stream) {
    const float* x      = (const float*)d_in[0];
    const float* state0 = (const float*)d_in[1];
    const float* W1     = (const float*)d_in[2];
    const float* b1     = (const float*)d_in[3];
    const float* Lam    = (const float*)d_in[4];

    float* ws  = (float*)d_ws;
    float* xT  = ws;                      // 131072 floats
    f2*    acT = (f2*)(ws + 131072);      // 131072 f2

    f4* out4 = (f4*)d_out;

    k_transpose_x<<<dim3(16, 8), 256, 0, stream>>>(x, xT);
    k_gemm_act<<<dim3(256), 256, 0, stream>>>(xT, W1, b1, Lam, acT);
    k_rec<<<dim3(256), 256, 0, stream>>>(x, state0, acT, out4);
}